// Round 12
// baseline (386.960 us; speedup 1.0000x reference)
//
#include <hip/hip_runtime.h>
#include <hip/hip_bf16.h>
#include <stdint.h>

#define HSZ 2048
#define PRIME 500009u
#define CHUNK 64   // K-floats staged per iteration (256 B/row)
#define NCH 32     // 2048 / 64
#define BUFB 8192  // bytes per staging buffer (32 rows x 256 B)
#define WGOFF 24576
#define IDXOFF 49152
#define REPS 5     // DIAGNOSTIC: repeat identical work to surface kernel in rocprof top-5

typedef __attribute__((ext_vector_type(8))) short short8;
typedef __attribute__((ext_vector_type(4))) float f32x4;
typedef __attribute__((ext_vector_type(4))) unsigned uint4v;
typedef __attribute__((ext_vector_type(2))) unsigned uint2v;

#define MEMFENCE asm volatile("" ::: "memory")
#define BARRIER() do { MEMFENCE; __builtin_amdgcn_s_barrier(); MEMFENCE; } while (0)
#define WAIT_LGKM0 asm volatile("s_waitcnt lgkmcnt(0)" ::: "memory")
#define WAIT_VM(n) asm volatile("s_waitcnt vmcnt(" #n ")" ::: "memory")

__device__ __forceinline__ unsigned pk2(float x, float y) {
  __hip_bfloat162 h = __float22bfloat162_rn(make_float2(x, y));
  return *reinterpret_cast<unsigned*>(&h);
}
__device__ __forceinline__ short f2bf(float f) {
  __hip_bfloat16 h = __float2bfloat16(f);
  return *reinterpret_cast<short*>(&h);
}
__device__ __forceinline__ short8 pack8(float4 a, float4 b) {
  uint4v u = {pk2(a.x, a.y), pk2(a.z, a.w), pk2(b.x, b.y), pk2(b.z, b.w)};
  return __builtin_bit_cast(short8, u);
}
__device__ __forceinline__ short8 load8_bf(const float* __restrict__ p) {
  float4 a = *reinterpret_cast<const float4*>(p);
  float4 b = *reinterpret_cast<const float4*>(p + 4);
  return pack8(a, b);
}
__device__ __forceinline__ void gload_lds16(const float* g, void* l) {
  __builtin_amdgcn_global_load_lds(
      (const __attribute__((address_space(1))) void*)g,
      (__attribute__((address_space(3))) void*)l, 16, 0, 0);
}

// ====== R11 kernel body, repeated REPS times per dispatch (pure diagnostic) ======
// Each rep writes identical values (idempotent). Rep N+1's first post-hash
// barrier precedes any overwrite of the aliased staging region, so reps are
// race-free under wave skew.
__global__ __launch_bounds__(256, 2) void engram_fused(
    const int* __restrict__ ids, const int* __restrict__ mapping,
    const unsigned* __restrict__ mult, const float* __restrict__ table,
    const float* __restrict__ Wh, const float* __restrict__ hidden,
    const float* __restrict__ cw, const float* __restrict__ cb,
    const float* __restrict__ Wg, const float* __restrict__ Wo,
    float* __restrict__ out) {
  __shared__ __align__(16) char smem[IDXOFF + 1152];
  int* idx_lds = (int*)(smem + IDXOFF);
  short(*A_lds)[264] = (short(*)[264])smem;
  float(*emb36)[36] = (float(*)[36])(smem + WGOFF);
  float(*emb_c)[33] = (float(*)[33])(smem + WGOFF + 5184);
  short(*ge_lds)[40] = (short(*)[40])(smem + WGOFF + 5184 + 4224);

  const int tid = threadIdx.x;
  const int wid = tid >> 6, lane = tid & 63;
  const int l16 = lane & 15, q = lane >> 4;
  const int t0 = blockIdx.x * 32;

  auto STAGE = [&](int buf, int kc) {
#pragma unroll
    for (int j = 0; j < 2; ++j) {
      int r0 = wid * 8 + j * 4;
      int r = r0 + (lane >> 4);
      unsigned c4 = (((unsigned)l16 * 16u) ^ (((unsigned)r & 7u) << 4)) >> 2;
      gload_lds16(hidden + (size_t)(t0 + r) * HSZ + kc * CHUNK + c4,
                  smem + buf * BUFB + r0 * 256);
    }
#pragma unroll
    for (int j = 0; j < 2; ++j) {
      int r0 = wid * 8 + j * 4;
      int r = r0 + (lane >> 4);
      unsigned c4 = (((unsigned)l16 * 16u) ^ (((unsigned)r & 7u) << 4)) >> 2;
      gload_lds16(Wg + (size_t)r * HSZ + kc * CHUNK + c4,
                  smem + WGOFF + buf * BUFB + r0 * 256);
    }
  };

  for (int rep = 0; rep < REPS; ++rep) {
    // ---- 1) hash ----
#pragma unroll
    for (int p = 0; p < 2; ++p) {
      int hh = p * 256 + tid;
      if (hh < 288) {
        int slot = hh >> 3, head = hh & 7;
        int tg = t0 - 4 + slot;
        if (tg < 0) tg = 0;
        int b = tg >> 12, s = tg & 4095;
        const int* idb = ids + (b << 12);
        int s1 = s + 1 > 4095 ? 4095 : s + 1;
        int s2 = s + 2 > 4095 ? 4095 : s + 2;
        uint64_t c0 = (unsigned)mapping[idb[s]];
        uint64_t c1 = (unsigned)mapping[idb[s1]];
        uint64_t c2 = (unsigned)mapping[idb[s2]];
        int mb = head * 3;
        uint64_t h = (c0 * (uint64_t)mult[mb]) ^ (c1 * (uint64_t)mult[mb + 1]);
        if (head >= 4) h ^= c2 * (uint64_t)mult[mb + 2];
        idx_lds[hh] = (int)((unsigned)(h % PRIME) + (unsigned)head * PRIME);
      }
    }
    WAIT_LGKM0; BARRIER();

    // ---- 2) gather held in VGPRs ----
    float4 g[9];
#pragma unroll
    for (int p = 0; p < 9; ++p) {
      int task = p * 256 + tid;
      int r = task >> 3, c4 = (task & 7) * 4;
      int row = idx_lds[r];
      g[p] = *reinterpret_cast<const float4*>(table + (size_t)row * 32 + c4);
    }

    // ---- 3) prologue staging ----
    STAGE(0, 0);
    STAGE(1, 1);
    STAGE(2, 2);

    // ---- 4) gate MLP ----
    const int tt = wid >> 1, ee = wid & 1;
    const int R = tt * 16 + l16;
    const unsigned sw = ((unsigned)R & 7u) << 4;
    const int Rb = ee * 16 + l16;
    const unsigned swb = ((unsigned)Rb & 7u) << 4;
    const char* hrow = smem + R * 256;
    const char* wrow = smem + WGOFF + Rb * 256;
    f32x4 acc = {0.f, 0.f, 0.f, 0.f};
    const unsigned x0 = q * 32u;

    auto MLP_ITER = [&](int kc) {
      const char* hb = hrow + (kc % 3) * BUFB;
      const char* wb = wrow + (kc % 3) * BUFB;
      float4 a0 = *reinterpret_cast<const float4*>(hb + (x0 ^ sw));
      float4 a1 = *reinterpret_cast<const float4*>(hb + ((x0 + 16) ^ sw));
      float4 a2 = *reinterpret_cast<const float4*>(hb + ((x0 + 128) ^ sw));
      float4 a3 = *reinterpret_cast<const float4*>(hb + ((x0 + 144) ^ sw));
      float4 b0 = *reinterpret_cast<const float4*>(wb + (x0 ^ swb));
      float4 b1 = *reinterpret_cast<const float4*>(wb + ((x0 + 16) ^ swb));
      float4 b2 = *reinterpret_cast<const float4*>(wb + ((x0 + 128) ^ swb));
      float4 b3 = *reinterpret_cast<const float4*>(wb + ((x0 + 144) ^ swb));
      short8 A0 = pack8(a0, a1), A1 = pack8(a2, a3);
      short8 B0 = pack8(b0, b1), B1 = pack8(b2, b3);
      WAIT_LGKM0;
      BARRIER();
      if (kc < NCH - 3) STAGE((kc + 3) % 3, kc + 3);
      acc = __builtin_amdgcn_mfma_f32_16x16x32_bf16(A0, B0, acc, 0, 0, 0);
      acc = __builtin_amdgcn_mfma_f32_16x16x32_bf16(A1, B1, acc, 0, 0, 0);
    };

    for (int kc = 0; kc < NCH - 2; ++kc) {
      WAIT_VM(8);
      BARRIER();
      MLP_ITER(kc);
    }
    { WAIT_VM(4); BARRIER(); MLP_ITER(NCH - 2); }
    { WAIT_VM(0); BARRIER(); MLP_ITER(NCH - 1); }

    // ---- 5) gathered rows -> A_lds bf16 ----
#pragma unroll
    for (int p = 0; p < 9; ++p) {
      int task = p * 256 + tid;
      int r = task >> 3, c4 = (task & 7) * 4;
      uint2v pk = {pk2(g[p].x, g[p].y), pk2(g[p].z, g[p].w)};
      *reinterpret_cast<uint2v*>(&A_lds[r >> 3][(r & 7) * 32 + c4]) = pk;
    }
    WAIT_LGKM0; BARRIER();

    // ---- 6) emb0 MFMA ----
    for (int job = wid; job < 6; job += 4) {
      int jt = job >> 1;
      int base = (jt == 0) ? 0 : (jt == 1) ? 16 : 20;
      int e0 = (job & 1) * 16;
      f32x4 ac = {0.f, 0.f, 0.f, 0.f};
#pragma unroll
      for (int ks = 0; ks < 8; ++ks) {
        short8 wf = load8_bf(Wh + (size_t)(e0 + l16) * 256 + ks * 32 + q * 8);
        short8 a = *reinterpret_cast<const short8*>(&A_lds[base + l16][ks * 32 + q * 8]);
        ac = __builtin_amdgcn_mfma_f32_16x16x32_bf16(wf, a, ac, 0, 0, 0);
      }
      if (jt != 2 || l16 >= 12)
        *reinterpret_cast<f32x4*>(&emb36[base + l16][e0 + q * 4]) = ac;
    }
    WAIT_LGKM0; BARRIER();

    // ---- 7) conv ----
#pragma unroll
    for (int it = 0; it < 4; ++it) {
      int ii = it * 256 + tid;
      int tl = ii >> 5, e = ii & 31;
      int s = (t0 & 4095) + tl;
      float a = cb[e];
#pragma unroll
      for (int j = 0; j < 4; ++j)
        if (s - 3 + j >= 0) a += cw[e * 4 + j] * emb36[tl + 1 + j][e];
      emb_c[tl][e] = a;
    }
    WAIT_LGKM0; BARRIER();

    // ---- 8) sigmoid * conv-emb -> ge_lds ----
#pragma unroll
    for (int j = 0; j < 4; ++j) {
      int r = tt * 16 + q * 4 + j, c = ee * 16 + l16;
      float gt = 1.f / (1.f + __expf(-acc[j]));
      ge_lds[r][c] = f2bf(gt * emb_c[r][c]);
    }
    WAIT_LGKM0; BARRIER();

    // ---- 9) out = ge @ Wo.T ----
    short8 Af0 = *reinterpret_cast<const short8*>(&ge_lds[l16][q * 8]);
    short8 Af1 = *reinterpret_cast<const short8*>(&ge_lds[16 + l16][q * 8]);
    float* orow0 = out + (size_t)(t0 + l16) * HSZ;
    float* orow1 = out + (size_t)(t0 + 16 + l16) * HSZ;
    int hbase = wid * 512;
#pragma unroll 4
    for (int ht = 0; ht < 32; ++ht) {
      int h0 = hbase + ht * 16;
      short8 aw = load8_bf(Wo + (size_t)(h0 + l16) * 32 + q * 8);
      f32x4 z = {0.f, 0.f, 0.f, 0.f};
      f32x4 o0 = __builtin_amdgcn_mfma_f32_16x16x32_bf16(aw, Af0, z, 0, 0, 0);
      f32x4 o1 = __builtin_amdgcn_mfma_f32_16x16x32_bf16(aw, Af1, z, 0, 0, 0);
      *reinterpret_cast<f32x4*>(orow0 + h0 + q * 4) = o0;
      *reinterpret_cast<f32x4*>(orow1 + h0 + q * 4) = o1;
    }
    // next rep's first post-hash barrier gates any staging overwrite
  }
}

extern "C" void kernel_launch(void* const* d_in, const int* in_sizes, int n_in,
                              void* d_out, int out_size, void* d_ws, size_t ws_size,
                              hipStream_t stream) {
  const int* ids = (const int*)d_in[0];
  const float* hidden = (const float*)d_in[1];
  const int* mapping = (const int*)d_in[2];
  const unsigned* mult = (const unsigned*)d_in[3];  // delivered as int32; low bits exact
  const float* table = (const float*)d_in[4];
  const float* cw = (const float*)d_in[5];
  const float* cb = (const float*)d_in[6];
  const float* Wh = (const float*)d_in[7];
  const float* Wg = (const float*)d_in[8];
  const float* Wo = (const float*)d_in[9];
  float* out = (float*)d_out;

  engram_fused<<<512, 256, 0, stream>>>(ids, mapping, mult, table, Wh, hidden,
                                        cw, cb, Wg, Wo, out);
}

// Round 13
// 114.646 us; speedup vs baseline: 3.3753x; 3.3753x over previous
//
#include <hip/hip_runtime.h>
#include <hip/hip_bf16.h>
#include <stdint.h>

#define HSZ 2048
#define PRIME 500009u

typedef __attribute__((ext_vector_type(8))) short short8;
typedef __attribute__((ext_vector_type(4))) float f32x4;
typedef __attribute__((ext_vector_type(4))) unsigned uint4v;
typedef __attribute__((ext_vector_type(2))) unsigned uint2v;

#define MEMFENCE asm volatile("" ::: "memory")
#define BARRIER() do { MEMFENCE; __builtin_amdgcn_s_barrier(); MEMFENCE; } while (0)
#define WAIT_LGKM0 asm volatile("s_waitcnt lgkmcnt(0)" ::: "memory")

__device__ __forceinline__ unsigned pk2(float x, float y) {
  __hip_bfloat162 h = __float22bfloat162_rn(make_float2(x, y));
  return *reinterpret_cast<unsigned*>(&h);
}
__device__ __forceinline__ short f2bf(float f) {
  __hip_bfloat16 h = __float2bfloat16(f);
  return *reinterpret_cast<short*>(&h);
}
__device__ __forceinline__ short8 pack8(float4 a, float4 b) {
  uint4v u = {pk2(a.x, a.y), pk2(a.z, a.w), pk2(b.x, b.y), pk2(b.z, b.w)};
  return __builtin_bit_cast(short8, u);
}
__device__ __forceinline__ short8 load8_bf(const float* __restrict__ p) {
  float4 a = *reinterpret_cast<const float4*>(p);
  float4 b = *reinterpret_cast<const float4*>(p + 4);
  return pack8(a, b);
}

// ============ fused kernel: 1024 blocks x 256 threads, 16 tokens/block ============
// Latency-bound redesign (R12 diagnostic: all pipes <13%, occupancy 20%):
//  - MLP is BARRIER-FREE: per-wave VGPR double-buffered K-chunks, no LDS staging,
//    Wg/hidden row sharing served by L2. Per-wave counted vmcnt comes free from
//    the compiler (in-order, private).
//  - LDS 19.5 KB + <=128 VGPR -> 4 blocks/CU = 16 independent waves/CU (2x prior).
__global__ __launch_bounds__(256, 4) void engram_fused(
    const int* __restrict__ ids, const int* __restrict__ mapping,
    const unsigned* __restrict__ mult, const float* __restrict__ table,
    const float* __restrict__ Wh, const float* __restrict__ hidden,
    const float* __restrict__ cw, const float* __restrict__ cb,
    const float* __restrict__ Wg, const float* __restrict__ Wo,
    float* __restrict__ out) {
  __shared__ int idx_lds[160];                   // 20 slots x 8 heads
  __shared__ __align__(16) short A_lds[20][264]; // gathered table rows, bf16
  __shared__ __align__(16) float emb20[20][36];  // emb0 for 20 slots
  __shared__ float emb_c[16][33];                // conv output
  __shared__ __align__(16) short ge_lds[16][40]; // gate*emb bf16
  __shared__ float accred[2][4][64];             // K-half reduce

  const int tid = threadIdx.x;
  const int wid = tid >> 6, lane = tid & 63;
  const int l16 = lane & 15, q = lane >> 4;
  const int t0 = blockIdx.x * 16;

  // ---- 1) hash: 20 slots x 8 heads = 160; slot s = token t0-4+s (clamped) ----
  if (tid < 160) {
    int slot = tid >> 3, head = tid & 7;
    int tg = t0 - 4 + slot;
    if (tg < 0) tg = 0;
    int b = tg >> 12, s = tg & 4095;
    const int* idb = ids + (b << 12);
    int s1 = s + 1 > 4095 ? 4095 : s + 1;
    int s2 = s + 2 > 4095 ? 4095 : s + 2;
    uint64_t c0 = (unsigned)mapping[idb[s]];
    uint64_t c1 = (unsigned)mapping[idb[s1]];
    uint64_t c2 = (unsigned)mapping[idb[s2]];
    int mb = head * 3;  // multipliers row-major [2][4][3]
    uint64_t h = (c0 * (uint64_t)mult[mb]) ^ (c1 * (uint64_t)mult[mb + 1]);
    if (head >= 4) h ^= c2 * (uint64_t)mult[mb + 2];
    idx_lds[tid] = (int)((unsigned)(h % PRIME) + (unsigned)head * PRIME);
  }
  WAIT_LGKM0; BARRIER();

  // ---- 2) gather 160 rows (128 B, 8 lanes/row; 5 float4/thread) -> A_lds bf16 ----
#pragma unroll
  for (int p = 0; p < 5; ++p) {
    int task = p * 256 + tid;  // 1280 tasks = 160 rows x 8 lane-groups
    int r = task >> 3, c4 = (task & 7) * 4;
    int row = idx_lds[r];
    float4 v = *reinterpret_cast<const float4*>(table + (size_t)row * 32 + c4);
    uint2v pk = {pk2(v.x, v.y), pk2(v.z, v.w)};
    *reinterpret_cast<uint2v*>(&A_lds[r >> 3][(r & 7) * 32 + c4]) = pk;
  }
  WAIT_LGKM0; BARRIER();

  // ---- 3) emb0 MFMA: 2 slot-tiles (bases 0,4) x 2 e-tiles = 4 jobs, 1/wave ----
  {
    int jt = wid >> 1, e0 = (wid & 1) * 16;
    int base = jt ? 4 : 0;
    f32x4 ac = {0.f, 0.f, 0.f, 0.f};
#pragma unroll
    for (int ks = 0; ks < 8; ++ks) {
      short8 wf = load8_bf(Wh + (size_t)(e0 + l16) * 256 + ks * 32 + q * 8);
      short8 a = *reinterpret_cast<const short8*>(&A_lds[base + l16][ks * 32 + q * 8]);
      ac = __builtin_amdgcn_mfma_f32_16x16x32_bf16(wf, a, ac, 0, 0, 0);
    }
    // D: col=slot(l16), row=e(q*4+j); tile 1 (base 4) writes only slots 16..19
    if (jt == 0 || l16 >= 12)
      *reinterpret_cast<f32x4*>(&emb20[base + l16][e0 + q * 4]) = ac;
  }
  WAIT_LGKM0; BARRIER();

  // ---- 4) conv: token t0+tl -> slots tl+1..tl+4 (batch zero-pad via guard) ----
#pragma unroll
  for (int it = 0; it < 2; ++it) {
    int ii = it * 256 + tid;
    int tl = ii >> 5, e = ii & 31;
    int s = (t0 & 4095) + tl;
    float a = cb[e];
#pragma unroll
    for (int j = 0; j < 4; ++j)
      if (s - 3 + j >= 0) a += cw[e * 4 + j] * emb20[tl + 1 + j][e];
    emb_c[tl][e] = a;
  }
  WAIT_LGKM0; BARRIER();

  // ---- 5) gate MLP: BARRIER-FREE. wave (ee,kh) = e-tile x K-half.
  //      VGPR double-buffer of K=32 chunks; 32 chunks per K-half. ----
  const int ee = wid & 1, kh = wid >> 1;
  const float* ha = hidden + (size_t)(t0 + l16) * HSZ + kh * 1024 + q * 8;
  const float* wb = Wg + (size_t)(ee * 16 + l16) * HSZ + kh * 1024 + q * 8;
  f32x4 acc = {0.f, 0.f, 0.f, 0.f};
  float4 a0c = *reinterpret_cast<const float4*>(ha);
  float4 a1c = *reinterpret_cast<const float4*>(ha + 4);
  float4 b0c = *reinterpret_cast<const float4*>(wb);
  float4 b1c = *reinterpret_cast<const float4*>(wb + 4);
  for (int i = 0; i < 15; ++i) {
    const float* h1 = ha + (2 * i + 1) * 32;
    const float* w1 = wb + (2 * i + 1) * 32;
    float4 a0n = *reinterpret_cast<const float4*>(h1);
    float4 a1n = *reinterpret_cast<const float4*>(h1 + 4);
    float4 b0n = *reinterpret_cast<const float4*>(w1);
    float4 b1n = *reinterpret_cast<const float4*>(w1 + 4);
    acc = __builtin_amdgcn_mfma_f32_16x16x32_bf16(pack8(a0c, a1c), pack8(b0c, b1c), acc, 0, 0, 0);
    const float* h2 = ha + (2 * i + 2) * 32;
    const float* w2 = wb + (2 * i + 2) * 32;
    a0c = *reinterpret_cast<const float4*>(h2);
    a1c = *reinterpret_cast<const float4*>(h2 + 4);
    b0c = *reinterpret_cast<const float4*>(w2);
    b1c = *reinterpret_cast<const float4*>(w2 + 4);
    acc = __builtin_amdgcn_mfma_f32_16x16x32_bf16(pack8(a0n, a1n), pack8(b0n, b1n), acc, 0, 0, 0);
  }
  {  // tail: c holds chunk 30; load+consume 31
    const float* h1 = ha + 31 * 32;
    const float* w1 = wb + 31 * 32;
    float4 a0n = *reinterpret_cast<const float4*>(h1);
    float4 a1n = *reinterpret_cast<const float4*>(h1 + 4);
    float4 b0n = *reinterpret_cast<const float4*>(w1);
    float4 b1n = *reinterpret_cast<const float4*>(w1 + 4);
    acc = __builtin_amdgcn_mfma_f32_16x16x32_bf16(pack8(a0c, a1c), pack8(b0c, b1c), acc, 0, 0, 0);
    acc = __builtin_amdgcn_mfma_f32_16x16x32_bf16(pack8(a0n, a1n), pack8(b0n, b1n), acc, 0, 0, 0);
  }

  // ---- 6) K-half reduce + sigmoid*emb -> ge_lds ----
  if (kh == 1) {
#pragma unroll
    for (int j = 0; j < 4; ++j) accred[ee][j][lane] = acc[j];
  }
  WAIT_LGKM0; BARRIER();
  if (kh == 0) {
#pragma unroll
    for (int j = 0; j < 4; ++j) {
      float s = acc[j] + accred[ee][j][lane];
      int r = q * 4 + j, c = ee * 16 + l16;  // D: col=gate-e(l16), row=token(q*4+j)
      float g = 1.f / (1.f + __expf(-s));
      ge_lds[r][c] = f2bf(g * emb_c[r][c]);
    }
  }
  WAIT_LGKM0; BARRIER();

  // ---- 7) out[t,h] = ge @ Wo.T (swapped -> float4 stores); 512 h-cols/wave ----
  short8 Af = *reinterpret_cast<const short8*>(&ge_lds[l16][q * 8]);
  float* orow = out + (size_t)(t0 + l16) * HSZ;
#pragma unroll 4
  for (int ht = 0; ht < 32; ++ht) {
    int h0 = wid * 512 + ht * 16;
    short8 aw = load8_bf(Wo + (size_t)(h0 + l16) * 32 + q * 8);
    f32x4 z = {0.f, 0.f, 0.f, 0.f};
    f32x4 o = __builtin_amdgcn_mfma_f32_16x16x32_bf16(aw, Af, z, 0, 0, 0);
    *reinterpret_cast<f32x4*>(orow + h0 + q * 4) = o;  // D: col=token, row=h
  }
}

extern "C" void kernel_launch(void* const* d_in, const int* in_sizes, int n_in,
                              void* d_out, int out_size, void* d_ws, size_t ws_size,
                              hipStream_t stream) {
  const int* ids = (const int*)d_in[0];
  const float* hidden = (const float*)d_in[1];
  const int* mapping = (const int*)d_in[2];
  const unsigned* mult = (const unsigned*)d_in[3];  // delivered as int32; low bits exact
  const float* table = (const float*)d_in[4];
  const float* cw = (const float*)d_in[5];
  const float* cb = (const float*)d_in[6];
  const float* Wh = (const float*)d_in[7];
  const float* Wg = (const float*)d_in[8];
  const float* Wo = (const float*)d_in[9];
  float* out = (float*)d_out;

  engram_fused<<<1024, 256, 0, stream>>>(ids, mapping, mult, table, Wh, hidden,
                                         cw, cb, Wg, Wo, out);
}

// Round 14
// 76.404 us; speedup vs baseline: 5.0647x; 1.5005x over previous
//
#include <hip/hip_runtime.h>
#include <hip/hip_bf16.h>
#include <stdint.h>

#define HSZ 2048
#define PRIME 500009u
#define CHUNK 64    // K-floats staged per iteration (256 B/row)
#define NCH 32      // 2048 / 64
#define BUFB 8192   // bytes per staging buffer (32 rows x 256 B)
#define WGOFF 16384 // Wg staging base
#define IDXOFF 32768
// post-MLP aliases into the (dead) staging region:
#define A_OFF 0      // A_lds[36][264] bf16 = 19008 B
#define E36_OFF 19008 // emb36[36][36] f32  = 5184 B
#define EC_OFF 24192  // emb_c[32][33] f32  = 4224 B
#define GE_OFF 28416  // ge_lds[32][40] bf16 = 2560 B  (ends 30976 < 32768)

typedef __attribute__((ext_vector_type(8))) short short8;
typedef __attribute__((ext_vector_type(4))) float f32x4;
typedef __attribute__((ext_vector_type(4))) unsigned uint4v;
typedef __attribute__((ext_vector_type(2))) unsigned uint2v;

#define MEMFENCE asm volatile("" ::: "memory")
#define BARRIER() do { MEMFENCE; __builtin_amdgcn_s_barrier(); MEMFENCE; } while (0)
#define WAIT_LGKM0 asm volatile("s_waitcnt lgkmcnt(0)" ::: "memory")
#define WAIT_VM(n) asm volatile("s_waitcnt vmcnt(" #n ")" ::: "memory")

__device__ __forceinline__ unsigned pk2(float x, float y) {
  __hip_bfloat162 h = __float22bfloat162_rn(make_float2(x, y));
  return *reinterpret_cast<unsigned*>(&h);
}
__device__ __forceinline__ short f2bf(float f) {
  __hip_bfloat16 h = __float2bfloat16(f);
  return *reinterpret_cast<short*>(&h);
}
__device__ __forceinline__ short8 pack8(float4 a, float4 b) {
  uint4v u = {pk2(a.x, a.y), pk2(a.z, a.w), pk2(b.x, b.y), pk2(b.z, b.w)};
  return __builtin_bit_cast(short8, u);
}
__device__ __forceinline__ short8 load8_bf(const float* __restrict__ p) {
  float4 a = *reinterpret_cast<const float4*>(p);
  float4 b = *reinterpret_cast<const float4*>(p + 4);
  return pack8(a, b);
}
__device__ __forceinline__ void gload_lds16(const float* g, void* l) {
  __builtin_amdgcn_global_load_lds(
      (const __attribute__((address_space(1))) void*)g,
      (__attribute__((address_space(3))) void*)l, 16, 0, 0);
}

// ============ fused kernel: 512 blocks x 256 threads, 32 tokens/block ============
// R11 pipeline, LDS dieted to 34 KB (double- instead of triple-buffered staging,
// post-MLP regions alias the dead staging bufs) + __launch_bounds__(256,4):
// 4 independent block pipelines per CU fill each other's barrier/latency stalls
// (R12 diagnostic: all pipes idle, occupancy 20% -> concurrency is the lever).
__global__ __launch_bounds__(256, 4) void engram_fused(
    const int* __restrict__ ids, const int* __restrict__ mapping,
    const unsigned* __restrict__ mult, const float* __restrict__ table,
    const float* __restrict__ Wh, const float* __restrict__ hidden,
    const float* __restrict__ cw, const float* __restrict__ cb,
    const float* __restrict__ Wg, const float* __restrict__ Wo,
    float* __restrict__ out) {
  __shared__ __align__(16) char smem[IDXOFF + 1152];  // 33,920 B total
  int* idx_lds = (int*)(smem + IDXOFF);
  short(*A_lds)[264] = (short(*)[264])(smem + A_OFF);
  float(*emb36)[36] = (float(*)[36])(smem + E36_OFF);
  float(*emb_c)[33] = (float(*)[33])(smem + EC_OFF);
  short(*ge_lds)[40] = (short(*)[40])(smem + GE_OFF);

  const int tid = threadIdx.x;
  const int wid = tid >> 6, lane = tid & 63;
  const int l16 = lane & 15, q = lane >> 4;
  const int t0 = blockIdx.x * 32;

  // stage one K-chunk: hidden rows t0..t0+31 -> buf, Wg rows 0..31 -> WGOFF+buf.
  // 4 vmem instrs per wave. LDS dest linear; global src col byte-XOR-swizzled
  // by ((row&7)<<4); read side applies the same XOR.
  auto STAGE = [&](int buf, int kc) {
#pragma unroll
    for (int j = 0; j < 2; ++j) {
      int r0 = wid * 8 + j * 4;
      int r = r0 + (lane >> 4);
      unsigned c4 = (((unsigned)l16 * 16u) ^ (((unsigned)r & 7u) << 4)) >> 2;
      gload_lds16(hidden + (size_t)(t0 + r) * HSZ + kc * CHUNK + c4,
                  smem + buf * BUFB + r0 * 256);
    }
#pragma unroll
    for (int j = 0; j < 2; ++j) {
      int r0 = wid * 8 + j * 4;
      int r = r0 + (lane >> 4);
      unsigned c4 = (((unsigned)l16 * 16u) ^ (((unsigned)r & 7u) << 4)) >> 2;
      gload_lds16(Wg + (size_t)r * HSZ + kc * CHUNK + c4,
                  smem + WGOFF + buf * BUFB + r0 * 256);
    }
  };

  // ---- 1) hash: 36 slots x 8 heads = 288; slot s = token t0-4+s (clamped) ----
#pragma unroll
  for (int p = 0; p < 2; ++p) {
    int hh = p * 256 + tid;
    if (hh < 288) {
      int slot = hh >> 3, head = hh & 7;
      int tg = t0 - 4 + slot;
      if (tg < 0) tg = 0;
      int b = tg >> 12, s = tg & 4095;
      const int* idb = ids + (b << 12);
      int s1 = s + 1 > 4095 ? 4095 : s + 1;
      int s2 = s + 2 > 4095 ? 4095 : s + 2;
      uint64_t c0 = (unsigned)mapping[idb[s]];
      uint64_t c1 = (unsigned)mapping[idb[s1]];
      uint64_t c2 = (unsigned)mapping[idb[s2]];
      int mb = head * 3;  // multipliers row-major [2][4][3]
      uint64_t h = (c0 * (uint64_t)mult[mb]) ^ (c1 * (uint64_t)mult[mb + 1]);
      if (head >= 4) h ^= c2 * (uint64_t)mult[mb + 2];
      idx_lds[hh] = (int)((unsigned)(h % PRIME) + (unsigned)head * PRIME);
    }
  }
  WAIT_LGKM0; BARRIER();

  // ---- 2) issue gather: 288 rows x 128 B, 9 float4/thread, HELD in VGPRs ----
  float4 g[9];
#pragma unroll
  for (int p = 0; p < 9; ++p) {
    int task = p * 256 + tid;  // 2304 tasks = 288 rows x 8 lane-groups
    int r = task >> 3, c4 = (task & 7) * 4;
    int row = idx_lds[r];
    g[p] = *reinterpret_cast<const float4*>(table + (size_t)row * 32 + c4);
  }

  // ---- 3) prologue: chunks 0,1 in flight (gathers older -> retired at iter 0) ----
  STAGE(0, 0);
  STAGE(1, 1);

  // ---- 4) gate MLP: wave (tt,ee) owns 16x16 tile, full K; depth-1 dbuf ----
  const int tt = wid >> 1, ee = wid & 1;
  const int R = tt * 16 + l16;
  const unsigned sw = ((unsigned)R & 7u) << 4;
  const int Rb = ee * 16 + l16;
  const unsigned swb = ((unsigned)Rb & 7u) << 4;
  const char* hrow = smem + R * 256;
  const char* wrow = smem + WGOFF + Rb * 256;
  f32x4 acc = {0.f, 0.f, 0.f, 0.f};
  const unsigned x0 = q * 32u;

  auto MLP_ITER = [&](int kc, bool stage_next) {
    const char* hb = hrow + (kc & 1) * BUFB;
    const char* wb = wrow + (kc & 1) * BUFB;
    float4 a0 = *reinterpret_cast<const float4*>(hb + (x0 ^ sw));
    float4 a1 = *reinterpret_cast<const float4*>(hb + ((x0 + 16) ^ sw));
    float4 a2 = *reinterpret_cast<const float4*>(hb + ((x0 + 128) ^ sw));
    float4 a3 = *reinterpret_cast<const float4*>(hb + ((x0 + 144) ^ sw));
    float4 b0 = *reinterpret_cast<const float4*>(wb + (x0 ^ swb));
    float4 b1 = *reinterpret_cast<const float4*>(wb + ((x0 + 16) ^ swb));
    float4 b2 = *reinterpret_cast<const float4*>(wb + ((x0 + 128) ^ swb));
    float4 b3 = *reinterpret_cast<const float4*>(wb + ((x0 + 144) ^ swb));
    short8 A0 = pack8(a0, a1), A1 = pack8(a2, a3);
    short8 B0 = pack8(b0, b1), B1 = pack8(b2, b3);
    WAIT_LGKM0;   // our ds_reads of chunk kc in regs
    BARRIER();    // every wave done reading buf[kc&1] -> safe to overwrite
    if (stage_next) STAGE(kc & 1, kc + 2);
    acc = __builtin_amdgcn_mfma_f32_16x16x32_bf16(A0, B0, acc, 0, 0, 0);
    acc = __builtin_amdgcn_mfma_f32_16x16x32_bf16(A1, B1, acc, 0, 0, 0);
  };

  for (int kc = 0; kc < NCH - 1; ++kc) {
    WAIT_VM(4);   // exact: stage(kc) retired (iter-0 also drains gather burst);
    BARRIER();    //        stage(kc+1)'s 4 instrs may still fly
    MLP_ITER(kc, kc < NCH - 2);
  }
  {  // kc = NCH-1: full drain
    WAIT_VM(0); BARRIER();
    MLP_ITER(NCH - 1, false);
  }

  // ---- 5) write gathered rows -> A_lds bf16 (aliases staging; all reads done) ----
#pragma unroll
  for (int p = 0; p < 9; ++p) {
    int task = p * 256 + tid;
    int r = task >> 3, c4 = (task & 7) * 4;
    uint2v pk = {pk2(g[p].x, g[p].y), pk2(g[p].z, g[p].w)};
    *reinterpret_cast<uint2v*>(&A_lds[r >> 3][(r & 7) * 32 + c4]) = pk;
  }
  WAIT_LGKM0; BARRIER();

  // ---- 6) emb0 MFMA: 3 slot-tiles (bases 0,16,20) x 2 e-tiles = 6 jobs ----
  for (int job = wid; job < 6; job += 4) {
    int jt = job >> 1;
    int base = (jt == 0) ? 0 : (jt == 1) ? 16 : 20;
    int e0 = (job & 1) * 16;
    f32x4 ac = {0.f, 0.f, 0.f, 0.f};
#pragma unroll
    for (int ks = 0; ks < 8; ++ks) {
      short8 wf = load8_bf(Wh + (size_t)(e0 + l16) * 256 + ks * 32 + q * 8);
      short8 a = *reinterpret_cast<const short8*>(&A_lds[base + l16][ks * 32 + q * 8]);
      ac = __builtin_amdgcn_mfma_f32_16x16x32_bf16(wf, a, ac, 0, 0, 0);
    }
    // D: col=slot(l16), row=e(q*4+j); tile 2 overlaps tile 1 -> only write slots >=32
    if (jt != 2 || l16 >= 12)
      *reinterpret_cast<f32x4*>(&emb36[base + l16][e0 + q * 4]) = ac;
  }
  WAIT_LGKM0; BARRIER();

  // ---- 7) conv: out token t0+tl needs slots tl+1..tl+4 (batch zero-pad) ----
#pragma unroll
  for (int it = 0; it < 4; ++it) {
    int ii = it * 256 + tid;
    int tl = ii >> 5, e = ii & 31;
    int s = (t0 & 4095) + tl;
    float a = cb[e];
#pragma unroll
    for (int j = 0; j < 4; ++j)
      if (s - 3 + j >= 0) a += cw[e * 4 + j] * emb36[tl + 1 + j][e];
    emb_c[tl][e] = a;
  }
  WAIT_LGKM0; BARRIER();

  // ---- 8) sigmoid * conv-emb -> ge_lds (acc held from MLP; wave quadrant) ----
#pragma unroll
  for (int j = 0; j < 4; ++j) {
    int r = tt * 16 + q * 4 + j, c = ee * 16 + l16;
    float gt = 1.f / (1.f + __expf(-acc[j]));
    ge_lds[r][c] = f2bf(gt * emb_c[r][c]);
  }
  WAIT_LGKM0; BARRIER();

  // ---- 9) out[t,h] = ge @ Wo.T (swapped -> float4 stores); 512 h-cols/wave ----
  short8 Af0 = *reinterpret_cast<const short8*>(&ge_lds[l16][q * 8]);
  short8 Af1 = *reinterpret_cast<const short8*>(&ge_lds[16 + l16][q * 8]);
  float* orow0 = out + (size_t)(t0 + l16) * HSZ;
  float* orow1 = out + (size_t)(t0 + 16 + l16) * HSZ;
  int hbase = wid * 512;
#pragma unroll 4
  for (int ht = 0; ht < 32; ++ht) {
    int h0 = hbase + ht * 16;
    short8 aw = load8_bf(Wo + (size_t)(h0 + l16) * 32 + q * 8);
    f32x4 z = {0.f, 0.f, 0.f, 0.f};
    f32x4 o0 = __builtin_amdgcn_mfma_f32_16x16x32_bf16(aw, Af0, z, 0, 0, 0);
    f32x4 o1 = __builtin_amdgcn_mfma_f32_16x16x32_bf16(aw, Af1, z, 0, 0, 0);
    *reinterpret_cast<f32x4*>(orow0 + h0 + q * 4) = o0;
    *reinterpret_cast<f32x4*>(orow1 + h0 + q * 4) = o1;
  }
}

extern "C" void kernel_launch(void* const* d_in, const int* in_sizes, int n_in,
                              void* d_out, int out_size, void* d_ws, size_t ws_size,
                              hipStream_t stream) {
  const int* ids = (const int*)d_in[0];
  const float* hidden = (const float*)d_in[1];
  const int* mapping = (const int*)d_in[2];
  const unsigned* mult = (const unsigned*)d_in[3];  // delivered as int32; low bits exact
  const float* table = (const float*)d_in[4];
  const float* cw = (const float*)d_in[5];
  const float* cb = (const float*)d_in[6];
  const float* Wh = (const float*)d_in[7];
  const float* Wg = (const float*)d_in[8];
  const float* Wo = (const float*)d_in[9];
  float* out = (float*)d_out;

  engram_fused<<<512, 256, 0, stream>>>(ids, mapping, mult, table, Wh, hidden,
                                        cw, cb, Wg, Wo, out);
}

// Round 15
// 74.934 us; speedup vs baseline: 5.1640x; 1.0196x over previous
//
#include <hip/hip_runtime.h>
#include <hip/hip_bf16.h>
#include <stdint.h>

#define HSZ 2048
#define PRIME 500009u
#define CHUNK 64      // K-floats per staged chunk (256 B/row)
#define NCH 32        // 2048 / 64
#define WAVE_REG 16384  // per-wave staging region: 2 bufs x (4KB hidden + 4KB Wg)
#define IDXOFF 65536
// post-MLP aliases into the (dead) staging region:
#define A_OFF 0       // A_lds[36][264] bf16 = 19008 B
#define E36_OFF 19008 // emb36[36][36] f32  = 5184 B
#define GE_OFF 24192  // ge_lds[32][40] bf16 = 2560 B (ends 26752)

typedef __attribute__((ext_vector_type(8))) short short8;
typedef __attribute__((ext_vector_type(4))) float f32x4;
typedef __attribute__((ext_vector_type(4))) unsigned uint4v;
typedef __attribute__((ext_vector_type(2))) unsigned uint2v;

#define MEMFENCE asm volatile("" ::: "memory")
#define BARRIER() do { MEMFENCE; __builtin_amdgcn_s_barrier(); MEMFENCE; } while (0)
#define WAIT_LGKM0 asm volatile("s_waitcnt lgkmcnt(0)" ::: "memory")
#define WAIT_VM(n) asm volatile("s_waitcnt vmcnt(" #n ")" ::: "memory")

__device__ __forceinline__ unsigned pk2(float x, float y) {
  __hip_bfloat162 h = __float22bfloat162_rn(make_float2(x, y));
  return *reinterpret_cast<unsigned*>(&h);
}
__device__ __forceinline__ short f2bf(float f) {
  __hip_bfloat16 h = __float2bfloat16(f);
  return *reinterpret_cast<short*>(&h);
}
__device__ __forceinline__ short8 pack8(float4 a, float4 b) {
  uint4v u = {pk2(a.x, a.y), pk2(a.z, a.w), pk2(b.x, b.y), pk2(b.z, b.w)};
  return __builtin_bit_cast(short8, u);
}
__device__ __forceinline__ short8 load8_bf(const float* __restrict__ p) {
  float4 a = *reinterpret_cast<const float4*>(p);
  float4 b = *reinterpret_cast<const float4*>(p + 4);
  return pack8(a, b);
}
__device__ __forceinline__ void gload_lds16(const float* g, void* l) {
  __builtin_amdgcn_global_load_lds(
      (const __attribute__((address_space(1))) void*)g,
      (__attribute__((address_space(3))) void*)l, 16, 0, 0);
}

// ============ fused kernel: 512 blocks x 256 threads, 32 tokens/block ============
// BARRIER-FREE MLP (R12 diagnostic: sync-bound, all pipes idle; R14: grid caps
// blocks/CU at 2, so more blocks is not available -> decouple the WAVES instead):
// each wave stages its own 16 hidden rows + 16 Wg rows per K-chunk into a private
// 16 KB LDS slice (global_load_lds, double-buffered, exact per-wave vmcnt).
// 8 independent wave-pipelines per CU, each with 16 KB in flight; no cross-wave
// sync for 32 iterations. Duplicated row fetch (2x) is absorbed by L2 (~3% used).
__global__ __launch_bounds__(256, 2) void engram_fused(
    const int* __restrict__ ids, const int* __restrict__ mapping,
    const unsigned* __restrict__ mult, const float* __restrict__ table,
    const float* __restrict__ Wh, const float* __restrict__ hidden,
    const float* __restrict__ cw, const float* __restrict__ cb,
    const float* __restrict__ Wg, const float* __restrict__ Wo,
    float* __restrict__ out) {
  __shared__ __align__(16) char smem[IDXOFF + 1152];  // 66,688 B -> 2 blocks/CU
  int* idx_lds = (int*)(smem + IDXOFF);
  short(*A_lds)[264] = (short(*)[264])(smem + A_OFF);
  float(*emb36)[36] = (float(*)[36])(smem + E36_OFF);
  short(*ge_lds)[40] = (short(*)[40])(smem + GE_OFF);

  const int tid = threadIdx.x;
  const int wid = tid >> 6, lane = tid & 63;
  const int l16 = lane & 15, q = lane >> 4;
  const int t0 = blockIdx.x * 32;
  const int tt = wid >> 1, ee = wid & 1;  // wave's token-tile / e-tile

  char* wavebase = smem + wid * WAVE_REG;

  // stage this wave's chunk kc: 16 hidden rows (tt*16..) + 16 Wg rows (ee*16..),
  // 256 B/row, 4+4 gload_lds16 instrs. LDS dest linear; global src col
  // byte-XOR-swizzled by ((r&7)<<4); read side applies the same XOR.
  auto STAGE = [&](int kc) {
    char* hb = wavebase + (kc & 1) * 8192;
#pragma unroll
    for (int j = 0; j < 4; ++j) {
      int r = j * 4 + q;  // local row this lane covers
      unsigned c4 = (((unsigned)l16 * 16u) ^ (((unsigned)r & 7u) << 4)) >> 2;
      gload_lds16(hidden + (size_t)(t0 + tt * 16 + r) * HSZ + kc * CHUNK + c4,
                  hb + j * 1024);
    }
#pragma unroll
    for (int j = 0; j < 4; ++j) {
      int r = j * 4 + q;
      unsigned c4 = (((unsigned)l16 * 16u) ^ (((unsigned)r & 7u) << 4)) >> 2;
      gload_lds16(Wg + (size_t)(ee * 16 + r) * HSZ + kc * CHUNK + c4,
                  hb + 4096 + j * 1024);
    }
  };

  // ---- 1) hash: 36 slots x 8 heads = 288; slot s = token t0-4+s (clamped) ----
#pragma unroll
  for (int p = 0; p < 2; ++p) {
    int hh = p * 256 + tid;
    if (hh < 288) {
      int slot = hh >> 3, head = hh & 7;
      int tg = t0 - 4 + slot;
      if (tg < 0) tg = 0;
      int b = tg >> 12, s = tg & 4095;
      const int* idb = ids + (b << 12);
      int s1 = s + 1 > 4095 ? 4095 : s + 1;
      int s2 = s + 2 > 4095 ? 4095 : s + 2;
      uint64_t c0 = (unsigned)mapping[idb[s]];
      uint64_t c1 = (unsigned)mapping[idb[s1]];
      uint64_t c2 = (unsigned)mapping[idb[s2]];
      int mb = head * 3;  // multipliers row-major [2][4][3]
      uint64_t h = (c0 * (uint64_t)mult[mb]) ^ (c1 * (uint64_t)mult[mb + 1]);
      if (head >= 4) h ^= c2 * (uint64_t)mult[mb + 2];
      idx_lds[hh] = (int)((unsigned)(h % PRIME) + (unsigned)head * PRIME);
    }
  }
  WAIT_LGKM0; BARRIER();

  // ---- 2) issue gather: 288 rows x 128 B, 9 float4/thread, HELD in VGPRs ----
  float4 g[9];
#pragma unroll
  for (int p = 0; p < 9; ++p) {
    int task = p * 256 + tid;  // 2304 tasks = 288 rows x 8 lane-groups
    int r = task >> 3, c4 = (task & 7) * 4;
    int row = idx_lds[r];
    g[p] = *reinterpret_cast<const float4*>(table + (size_t)row * 32 + c4);
  }

  // ---- 3) prologue: this wave's chunks 0,1 in flight ----
  STAGE(0);
  STAGE(1);

  // ---- 4) gate MLP: BARRIER-FREE, wave-private; full K per wave ----
  const unsigned swz = ((unsigned)l16 & 7u) << 4;
  const char* hrow = wavebase + l16 * 256;
  const char* wrow = wavebase + 4096 + l16 * 256;
  const unsigned x0 = q * 32u;
  f32x4 acc = {0.f, 0.f, 0.f, 0.f};

  auto MLP_ITER = [&](int kc, bool stage_next) {
    const char* hb = hrow + (kc & 1) * 8192;
    const char* wb = wrow + (kc & 1) * 8192;
    float4 a0 = *reinterpret_cast<const float4*>(hb + (x0 ^ swz));
    float4 a1 = *reinterpret_cast<const float4*>(hb + ((x0 + 16) ^ swz));
    float4 a2 = *reinterpret_cast<const float4*>(hb + ((x0 + 128) ^ swz));
    float4 a3 = *reinterpret_cast<const float4*>(hb + ((x0 + 144) ^ swz));
    float4 b0 = *reinterpret_cast<const float4*>(wb + (x0 ^ swz));
    float4 b1 = *reinterpret_cast<const float4*>(wb + ((x0 + 16) ^ swz));
    float4 b2 = *reinterpret_cast<const float4*>(wb + ((x0 + 128) ^ swz));
    float4 b3 = *reinterpret_cast<const float4*>(wb + ((x0 + 144) ^ swz));
    short8 A0 = pack8(a0, a1), A1 = pack8(a2, a3);
    short8 B0 = pack8(b0, b1), B1 = pack8(b2, b3);
    WAIT_LGKM0;                    // our ds_reads of chunk kc are in regs
    if (stage_next) STAGE(kc + 2); // now safe to overwrite buf[kc&1]
    acc = __builtin_amdgcn_mfma_f32_16x16x32_bf16(A0, B0, acc, 0, 0, 0);
    acc = __builtin_amdgcn_mfma_f32_16x16x32_bf16(A1, B1, acc, 0, 0, 0);
  };

  for (int kc = 0; kc < NCH - 1; ++kc) {
    WAIT_VM(8);  // exact per-wave: stage(kc) landed (iter-0 also retires gathers);
    MLP_ITER(kc, kc < NCH - 2);  // stage(kc+1)'s 8 instrs may still fly
  }
  { WAIT_VM(0); MLP_ITER(NCH - 1, false); }  // final chunk, full drain

  // ---- 5) all waves done with staging region -> write gathered rows as bf16 ----
  BARRIER();
#pragma unroll
  for (int p = 0; p < 9; ++p) {
    int task = p * 256 + tid;
    int r = task >> 3, c4 = (task & 7) * 4;
    uint2v pk = {pk2(g[p].x, g[p].y), pk2(g[p].z, g[p].w)};
    *reinterpret_cast<uint2v*>(&A_lds[r >> 3][(r & 7) * 32 + c4]) = pk;
  }
  WAIT_LGKM0; BARRIER();

  // ---- 6) emb0 MFMA: 3 slot-tiles (bases 0,16,20) x 2 e-tiles = 6 jobs ----
  for (int job = wid; job < 6; job += 4) {
    int jt = job >> 1;
    int base = (jt == 0) ? 0 : (jt == 1) ? 16 : 20;
    int e0 = (job & 1) * 16;
    f32x4 ac = {0.f, 0.f, 0.f, 0.f};
#pragma unroll
    for (int ks = 0; ks < 8; ++ks) {
      short8 wf = load8_bf(Wh + (size_t)(e0 + l16) * 256 + ks * 32 + q * 8);
      short8 a = *reinterpret_cast<const short8*>(&A_lds[base + l16][ks * 32 + q * 8]);
      ac = __builtin_amdgcn_mfma_f32_16x16x32_bf16(wf, a, ac, 0, 0, 0);
    }
    // D: col=slot(l16), row=e(q*4+j); tile 2 overlaps tile 1 -> only write slots >=32
    if (jt != 2 || l16 >= 12)
      *reinterpret_cast<f32x4*>(&emb36[base + l16][e0 + q * 4]) = ac;
  }
  WAIT_LGKM0; BARRIER();

  // ---- 7) conv + sigmoid fused: lane owns (rows tt*16+q*4+j, col ee*16+l16) ----
  {
    int c = ee * 16 + l16;
    float4 cwv = *reinterpret_cast<const float4*>(cw + c * 4);
    float cbv = cb[c];
#pragma unroll
    for (int j = 0; j < 4; ++j) {
      int r = tt * 16 + q * 4 + j;
      int s = (t0 & 4095) + r;
      float v = cbv;
#pragma unroll
      for (int j2 = 0; j2 < 4; ++j2)
        if (s - 3 + j2 >= 0) v += cwv[j2] * emb36[r + 1 + j2][c];  // token t0+r = slot r+4
      float gt = 1.f / (1.f + __expf(-acc[j]));
      ge_lds[r][c] = f2bf(gt * v);
    }
  }
  WAIT_LGKM0; BARRIER();

  // ---- 8) out[t,h] = ge @ Wo.T (swapped -> float4 stores); 512 h-cols/wave ----
  short8 Af0 = *reinterpret_cast<const short8*>(&ge_lds[l16][q * 8]);
  short8 Af1 = *reinterpret_cast<const short8*>(&ge_lds[16 + l16][q * 8]);
  float* orow0 = out + (size_t)(t0 + l16) * HSZ;
  float* orow1 = out + (size_t)(t0 + 16 + l16) * HSZ;
  int hbase = wid * 512;
#pragma unroll 4
  for (int ht = 0; ht < 32; ++ht) {
    int h0 = hbase + ht * 16;
    short8 aw = load8_bf(Wo + (size_t)(h0 + l16) * 32 + q * 8);
    f32x4 z = {0.f, 0.f, 0.f, 0.f};
    f32x4 o0 = __builtin_amdgcn_mfma_f32_16x16x32_bf16(aw, Af0, z, 0, 0, 0);
    f32x4 o1 = __builtin_amdgcn_mfma_f32_16x16x32_bf16(aw, Af1, z, 0, 0, 0);
    *reinterpret_cast<f32x4*>(orow0 + h0 + q * 4) = o0;
    *reinterpret_cast<f32x4*>(orow1 + h0 + q * 4) = o1;
  }
}

extern "C" void kernel_launch(void* const* d_in, const int* in_sizes, int n_in,
                              void* d_out, int out_size, void* d_ws, size_t ws_size,
                              hipStream_t stream) {
  const int* ids = (const int*)d_in[0];
  const float* hidden = (const float*)d_in[1];
  const int* mapping = (const int*)d_in[2];
  const unsigned* mult = (const unsigned*)d_in[3];  // delivered as int32; low bits exact
  const float* table = (const float*)d_in[4];
  const float* cw = (const float*)d_in[5];
  const float* cb = (const float*)d_in[6];
  const float* Wh = (const float*)d_in[7];
  const float* Wg = (const float*)d_in[8];
  const float* Wo = (const float*)d_in[9];
  float* out = (float*)d_out;

  engram_fused<<<512, 256, 0, stream>>>(ids, mapping, mult, table, Wh, hidden,
                                        cw, cb, Wg, Wo, out);
}